// Round 7
// baseline (81.309 us; speedup 1.0000x reference)
//
#include <hip/hip_runtime.h>

#define NB    8
#define NIN   512
#define TOUT  4096
#define ND    384
#define J4    (ND / 4)     // 96 float4 per row
#define TROWS 128          // output rows per block (preamble amortized 4x vs 32)
#define BLK   256          // threads per block (4 waves)

typedef float f32x4 __attribute__((ext_vector_type(4)));

// Fused length-regulator: per-block scan of ds[b], binary-search owner per
// output frame, streamed float4 stores. Plain stores through L2 (NT stores
// measured 25% slower on gfx950 - R6). 256 blocks = 1/CU: one scan preamble
// per CU instead of 4 redundant co-resident ones.
__global__ __launch_bounds__(BLK) void lenreg(const f32x4* __restrict__ xs,
                                              const int* __restrict__ ds,
                                              f32x4* __restrict__ out) {
    const int b       = blockIdx.x & 7;             // batch -> XCD pin
    const int rowbase = (blockIdx.x >> 3) * TROWS;  // first output frame
    const int tid     = threadIdx.x;

    __shared__ int cum[NIN];        // inclusive scan of ds[b]
    __shared__ int wsum[BLK / 64];  // per-wave scan totals
    __shared__ int owner[TROWS];    // owning token per row (-1 = empty)

    // ---- Phase A: inclusive scan of ds[b][0..511] (each thread 2 elems) ----
    const int* dsb = ds + b * NIN;
    const int a0 = dsb[2 * tid];
    const int a1 = dsb[2 * tid + 1];
    int p = a0 + a1;                // pair sum
    const int lane = tid & 63;
    const int wid  = tid >> 6;
    #pragma unroll
    for (int off = 1; off < 64; off <<= 1) {
        int v = __shfl_up(p, off, 64);
        if (lane >= off) p += v;
    }
    if (lane == 63) wsum[wid] = p;
    __syncthreads();
    int acc = 0;
    #pragma unroll
    for (int w = 0; w < BLK / 64; ++w)
        if (w < wid) acc += wsum[w];
    p += acc;                       // inclusive scan of pair sums
    cum[2 * tid + 1] = p;
    cum[2 * tid]     = p - a1;
    __syncthreads();

    // ---- Phase B: owner token for each of this block's TROWS rows ----
    const int total = cum[NIN - 1];
    if (tid < TROWS) {
        const int t = rowbase + tid;
        int o = -1;
        if (t < total) {            // lower_bound: smallest i with cum[i] > t
            int lo = 0, hi = NIN;
            // 10 guarded steps (range 512): 9 can leave hi-lo==1 untested.
            #pragma unroll
            for (int s = 0; s < 10; ++s) {
                if (lo < hi) {
                    int mid = (lo + hi) >> 1;
                    if (cum[mid] > t) hi = mid; else lo = mid + 1;
                }
            }
            o = lo;                 // zero-length tokens skipped automatically
        }
        owner[tid] = o;
    }
    __syncthreads();

    // ---- Phase C: stream TROWS rows of float4, fully coalesced ----
    const f32x4* xsb  = xs + (size_t)b * NIN * J4;
    f32x4*       outb = out + ((size_t)b * TOUT + rowbase) * J4;
    #pragma unroll 8
    for (int k = 0; k < TROWS * J4 / BLK; ++k) {   // 48 iterations
        const int g = k * BLK + tid;               // 0..12287
        const int r = g / J4;                      // row within tile
        const int j = g - r * J4;                  // float4 within row
        const int o = owner[r];
        f32x4 v = (f32x4)(0.f);
        if (o >= 0) v = xsb[o * J4 + j];
        outb[g] = v;
    }
}

extern "C" void kernel_launch(void* const* d_in, const int* in_sizes, int n_in,
                              void* d_out, int out_size, void* d_ws, size_t ws_size,
                              hipStream_t stream) {
    const float* xs = (const float*)d_in[0];   // (8, 512, 384) f32
    const int*   ds = (const int*)d_in[1];     // (8, 512) int
    float* out = (float*)d_out;                // (8, 4096, 384) f32

    // 1D grid: low 3 bits = batch (XCD slot), high bits = row tile
    lenreg<<<(TOUT / TROWS) * NB, BLK, 0, stream>>>((const f32x4*)xs, ds,
                                                    (f32x4*)out);
}

// Round 8
// 74.075 us; speedup vs baseline: 1.0976x; 1.0976x over previous
//
#include <hip/hip_runtime.h>

#define NB    8
#define NIN   512
#define TOUT  4096
#define ND    384
#define J4    (ND / 4)     // 96 float4 per row
#define TROWS 16           // output rows per block
#define BLK   256          // threads per block (4 waves)

typedef float f32x4 __attribute__((ext_vector_type(4)));

// Fused length-regulator: per-block scan of ds[b], binary-search owner per
// output frame, streamed float4 stores. R7 showed the store stream is
// latency-bound on the xs loads: 1 block/CU cost +6us vs 4 blocks/CU.
// -> max occupancy: 2048 blocks = 8 blocks/CU = 32 waves/CU, and full
// unroll so each wave keeps all 6 xs loads in flight before storing.
__global__ __launch_bounds__(BLK) void lenreg(const f32x4* __restrict__ xs,
                                              const int* __restrict__ ds,
                                              f32x4* __restrict__ out) {
    const int b       = blockIdx.x & 7;             // batch -> XCD pin
    const int rowbase = (blockIdx.x >> 3) * TROWS;  // first output frame
    const int tid     = threadIdx.x;

    __shared__ int cum[NIN];        // inclusive scan of ds[b]
    __shared__ int wsum[BLK / 64];  // per-wave scan totals
    __shared__ int owner[TROWS];    // owning token per row (-1 = empty)

    // ---- Phase A: inclusive scan of ds[b][0..511] (each thread 2 elems) ----
    const int* dsb = ds + b * NIN;
    const int a0 = dsb[2 * tid];
    const int a1 = dsb[2 * tid + 1];
    int p = a0 + a1;                // pair sum
    const int lane = tid & 63;
    const int wid  = tid >> 6;
    #pragma unroll
    for (int off = 1; off < 64; off <<= 1) {
        int v = __shfl_up(p, off, 64);
        if (lane >= off) p += v;
    }
    if (lane == 63) wsum[wid] = p;
    __syncthreads();
    int acc = 0;
    #pragma unroll
    for (int w = 0; w < BLK / 64; ++w)
        if (w < wid) acc += wsum[w];
    p += acc;                       // inclusive scan of pair sums
    cum[2 * tid + 1] = p;
    cum[2 * tid]     = p - a1;
    __syncthreads();

    // ---- Phase B: owner token for each of this block's TROWS rows ----
    const int total = cum[NIN - 1];
    if (tid < TROWS) {
        const int t = rowbase + tid;
        int o = -1;
        if (t < total) {            // lower_bound: smallest i with cum[i] > t
            int lo = 0, hi = NIN;
            // 10 guarded steps (range 512): 9 can leave hi-lo==1 untested.
            #pragma unroll
            for (int s = 0; s < 10; ++s) {
                if (lo < hi) {
                    int mid = (lo + hi) >> 1;
                    if (cum[mid] > t) hi = mid; else lo = mid + 1;
                }
            }
            o = lo;                 // zero-length tokens skipped automatically
        }
        owner[tid] = o;
    }
    __syncthreads();

    // ---- Phase C: 6 fully-unrolled load->store pairs, loads first ----
    const f32x4* xsb  = xs + (size_t)b * NIN * J4;
    f32x4*       outb = out + ((size_t)b * TOUT + rowbase) * J4;
    constexpr int ITER = TROWS * J4 / BLK;          // 6
    f32x4 v[ITER];
    #pragma unroll
    for (int k = 0; k < ITER; ++k) {
        const int g = k * BLK + tid;                // 0..1535
        const int o = owner[g / J4];
        v[k] = (f32x4)(0.f);
        if (o >= 0) v[k] = xsb[o * J4 + (g - (g / J4) * J4)];
    }
    #pragma unroll
    for (int k = 0; k < ITER; ++k)
        outb[k * BLK + tid] = v[k];
}

extern "C" void kernel_launch(void* const* d_in, const int* in_sizes, int n_in,
                              void* d_out, int out_size, void* d_ws, size_t ws_size,
                              hipStream_t stream) {
    const float* xs = (const float*)d_in[0];   // (8, 512, 384) f32
    const int*   ds = (const int*)d_in[1];     // (8, 512) int
    float* out = (float*)d_out;                // (8, 4096, 384) f32

    // 1D grid: low 3 bits = batch (XCD slot), high bits = row tile
    lenreg<<<(TOUT / TROWS) * NB, BLK, 0, stream>>>((const f32x4*)xs, ds,
                                                    (f32x4*)out);
}